// Round 5
// baseline (93.698 us; speedup 1.0000x reference)
//
#include <hip/hip_runtime.h>
#include <hip/hip_cooperative_groups.h>

namespace cg = cooperative_groups;

// ClipCluLoss: inputs [B=1024, T=32, D=1024] fp32 -> scalar fp32.
// dist[b] = T - (1/T) * || sum_t x_n[b,t,:] ||^2 ; out = mean_b dist[b].
//
// Single cooperative dispatch: 512 blocks x 512 threads (2 blocks/CU,
// exactly co-resident). Each block handles samples b and b+512 with the
// second sample's loads issued BEFORE the first sample's LDS epilogue
// (latency hides under the combine). Block 0 reduces after grid sync.

#define TT 32
#define DD 1024
#define BB 1024
#define GRID 512

__global__ __launch_bounds__(512, 4) void clip_fused_kernel(
    const float* __restrict__ x, float* __restrict__ partial,
    float* __restrict__ out) {
  const int lane = threadIdx.x & 63;
  const int wave = threadIdx.x >> 6;  // 0..7

  __shared__ float4 sacc[8 * 4 * 64];  // 32 KB: [wave][chunk][lane]
  __shared__ float wsum[4];
  __shared__ float w2[8];

  const int b0 = blockIdx.x;
  const int b1 = blockIdx.x + GRID;

  // ---- Load sample 0 slice: 4 rows x 4 chunks of float4, all coalesced.
  float4 v[4][4];
  {
    const float* __restrict__ xb = x + (size_t)b0 * (TT * DD);
#pragma unroll
    for (int r = 0; r < 4; ++r)
#pragma unroll
      for (int i = 0; i < 4; ++i)
        v[r][i] = *reinterpret_cast<const float4*>(
            xb + (wave * 4 + r) * DD + i * 256 + lane * 4);
  }

#pragma unroll
  for (int s = 0; s < 2; ++s) {
    const int b = (s == 0) ? b0 : b1;

    // ---- Row norms (rows are wave-local; butterfly leaves sum in all lanes).
    float inv[4];
#pragma unroll
    for (int r = 0; r < 4; ++r) {
      float ss = 0.0f;
#pragma unroll
      for (int i = 0; i < 4; ++i)
        ss += v[r][i].x * v[r][i].x + v[r][i].y * v[r][i].y +
              v[r][i].z * v[r][i].z + v[r][i].w * v[r][i].w;
#pragma unroll
      for (int off = 32; off; off >>= 1) ss += __shfl_xor(ss, off);
      inv[r] = 1.0f / fmaxf(sqrtf(ss), 1e-12f);
    }

    // ---- Per-wave weighted column sums (v consumed here, then dead).
    float4 a[4];
#pragma unroll
    for (int i = 0; i < 4; ++i) {
      a[i] = make_float4(0.f, 0.f, 0.f, 0.f);
#pragma unroll
      for (int r = 0; r < 4; ++r) {
        a[i].x = fmaf(v[r][i].x, inv[r], a[i].x);
        a[i].y = fmaf(v[r][i].y, inv[r], a[i].y);
        a[i].z = fmaf(v[r][i].z, inv[r], a[i].z);
        a[i].w = fmaf(v[r][i].w, inv[r], a[i].w);
      }
    }

    // ---- Prefetch sample 1 NOW: its HBM latency hides under the epilogue.
    if (s == 0) {
      const float* __restrict__ xb1 = x + (size_t)b1 * (TT * DD);
#pragma unroll
      for (int r = 0; r < 4; ++r)
#pragma unroll
        for (int i = 0; i < 4; ++i)
          v[r][i] = *reinterpret_cast<const float4*>(
              xb1 + (wave * 4 + r) * DD + i * 256 + lane * 4);
    }

    // ---- Cross-wave combine via LDS (conflict-free lane-contiguous).
#pragma unroll
    for (int i = 0; i < 4; ++i) sacc[(wave * 4 + i) * 64 + lane] = a[i];
    __syncthreads();

    float local = 0.0f;
    if (threadIdx.x < 256) {
      const int i = threadIdx.x >> 6;
      float4 t4s = make_float4(0.f, 0.f, 0.f, 0.f);
#pragma unroll
      for (int w = 0; w < 8; ++w) {
        const float4 t4 = sacc[(w * 4 + i) * 64 + lane];
        t4s.x += t4.x;
        t4s.y += t4.y;
        t4s.z += t4.z;
        t4s.w += t4.w;
      }
      local = t4s.x * t4s.x + t4s.y * t4s.y + t4s.z * t4s.z + t4s.w * t4s.w;
    }
#pragma unroll
    for (int off = 32; off; off >>= 1) local += __shfl_xor(local, off);
    if (wave < 4 && lane == 0) wsum[wave] = local;
    __syncthreads();  // also protects sacc reuse by next sample
    if (threadIdx.x == 0) {
      const float s2 = wsum[0] + wsum[1] + wsum[2] + wsum[3];
      partial[b] = (float)TT - s2 * (1.0f / (float)TT);
    }
  }

  // ---- Grid-wide sync, then block 0 reduces the 1024 partials.
  cg::this_grid().sync();
  if (blockIdx.x == 0) {
    float sred = partial[threadIdx.x] + partial[threadIdx.x + 512];
#pragma unroll
    for (int off = 32; off; off >>= 1) sred += __shfl_xor(sred, off);
    if (lane == 0) w2[wave] = sred;
    __syncthreads();
    if (threadIdx.x == 0) {
      float tot = 0.0f;
#pragma unroll
      for (int i = 0; i < 8; ++i) tot += w2[i];
      out[0] = tot * (1.0f / (float)BB);
    }
  }
}

// ---------- Fallback two-kernel path (used only if cooperative launch
// is rejected by the runtime / graph capture). ----------

__global__ __launch_bounds__(512, 4) void clip_partial_kernel(
    const float* __restrict__ x, float* __restrict__ partial) {
  const int b = blockIdx.x;
  const float* __restrict__ xb = x + (size_t)b * (TT * DD);
  const int lane = threadIdx.x & 63;
  const int wave = threadIdx.x >> 6;

  __shared__ float4 sacc[8 * 4 * 64];
  __shared__ float wsum[4];

  float4 v[4][4];
#pragma unroll
  for (int r = 0; r < 4; ++r)
#pragma unroll
    for (int i = 0; i < 4; ++i)
      v[r][i] = *reinterpret_cast<const float4*>(xb + (wave * 4 + r) * DD +
                                                 i * 256 + lane * 4);

  float inv[4];
#pragma unroll
  for (int r = 0; r < 4; ++r) {
    float ss = 0.0f;
#pragma unroll
    for (int i = 0; i < 4; ++i)
      ss += v[r][i].x * v[r][i].x + v[r][i].y * v[r][i].y +
            v[r][i].z * v[r][i].z + v[r][i].w * v[r][i].w;
#pragma unroll
    for (int off = 32; off; off >>= 1) ss += __shfl_xor(ss, off);
    inv[r] = 1.0f / fmaxf(sqrtf(ss), 1e-12f);
  }

#pragma unroll
  for (int i = 0; i < 4; ++i) {
    float4 a = make_float4(0.f, 0.f, 0.f, 0.f);
#pragma unroll
    for (int r = 0; r < 4; ++r) {
      a.x = fmaf(v[r][i].x, inv[r], a.x);
      a.y = fmaf(v[r][i].y, inv[r], a.y);
      a.z = fmaf(v[r][i].z, inv[r], a.z);
      a.w = fmaf(v[r][i].w, inv[r], a.w);
    }
    sacc[(wave * 4 + i) * 64 + lane] = a;
  }
  __syncthreads();

  float local = 0.0f;
  if (threadIdx.x < 256) {
    const int i = threadIdx.x >> 6;
    float4 s4 = make_float4(0.f, 0.f, 0.f, 0.f);
#pragma unroll
    for (int w = 0; w < 8; ++w) {
      const float4 t4 = sacc[(w * 4 + i) * 64 + lane];
      s4.x += t4.x;
      s4.y += t4.y;
      s4.z += t4.z;
      s4.w += t4.w;
    }
    local = s4.x * s4.x + s4.y * s4.y + s4.z * s4.z + s4.w * s4.w;
  }
#pragma unroll
  for (int off = 32; off; off >>= 1) local += __shfl_xor(local, off);
  if (wave < 4 && lane == 0) wsum[wave] = local;
  __syncthreads();
  if (threadIdx.x == 0) {
    const float s2 = wsum[0] + wsum[1] + wsum[2] + wsum[3];
    partial[b] = (float)TT - s2 * (1.0f / (float)TT);
  }
}

__global__ __launch_bounds__(256) void clip_reduce_kernel(
    const float* __restrict__ partial, float* __restrict__ out) {
  const int lane = threadIdx.x & 63;
  const int wave = threadIdx.x >> 6;
  const float4 v =
      *reinterpret_cast<const float4*>(partial + threadIdx.x * 4);
  float s = v.x + v.y + v.z + v.w;
#pragma unroll
  for (int off = 32; off; off >>= 1) s += __shfl_xor(s, off);
  __shared__ float wsum[4];
  if (lane == 0) wsum[wave] = s;
  __syncthreads();
  if (threadIdx.x == 0)
    out[0] = (wsum[0] + wsum[1] + wsum[2] + wsum[3]) * (1.0f / (float)BB);
}

extern "C" void kernel_launch(void* const* d_in, const int* in_sizes, int n_in,
                              void* d_out, int out_size, void* d_ws,
                              size_t ws_size, hipStream_t stream) {
  const float* x = (const float*)d_in[0];
  float* partial = (float*)d_ws;  // 1024 floats = 4 KB scratch
  float* out = (float*)d_out;

  void* args[] = {(void*)&x, (void*)&partial, (void*)&out};
  hipError_t err = hipLaunchCooperativeKernel(
      reinterpret_cast<void*>(clip_fused_kernel), dim3(GRID), dim3(512), args,
      0, stream);
  if (err != hipSuccess) {
    // Graph-capture or runtime refused cooperative launch: two-kernel path.
    clip_partial_kernel<<<BB, 512, 0, stream>>>(x, partial);
    clip_reduce_kernel<<<1, 256, 0, stream>>>(partial, out);
  }
}

// Round 6
// 62.856 us; speedup vs baseline: 1.4907x; 1.4907x over previous
//
#include <hip/hip_runtime.h>

// ClipCluLoss: inputs [B=1024, T=32, D=1024] fp32 -> scalar fp32.
// dist[b] = T - (1/T) * || sum_t x_n[b,t,:] ||^2 ; out = mean_b dist[b].
//
// Single HBM pass, single dispatch. Block = 1 sample, 512 threads (8 waves).
// Wave w owns rows w*4..w*4+3 (norm butterfly is wave-local, inv stays in
// registers). Lane l owns cols {i*256 + l*4}, so every global load is a
// contiguous 1 KB wave transaction.
// Final mean: ticket pattern — last block to finish reduces the 1024
// partials in a FIXED order (deterministic). Ticket zeroed by a memset node.

#define TT 32
#define DD 1024
#define BB 1024

__global__ __launch_bounds__(512, 4) void clip_kernel(
    const float* __restrict__ x, float* __restrict__ partial,
    unsigned int* __restrict__ ticket, float* __restrict__ out) {
  const int b = blockIdx.x;
  const float* __restrict__ xb = x + (size_t)b * (TT * DD);
  const int lane = threadIdx.x & 63;
  const int wave = threadIdx.x >> 6;  // 0..7

  __shared__ float4 sacc[8 * 4 * 64];  // 32 KB: [wave][chunk][lane]
  __shared__ float wsum[4];
  __shared__ bool is_last;
  __shared__ float w2[8];

  // ---- Load slice into registers: 4 rows x 4 chunks of float4, coalesced.
  float4 v[4][4];
#pragma unroll
  for (int r = 0; r < 4; ++r)
#pragma unroll
    for (int i = 0; i < 4; ++i)
      v[r][i] = *reinterpret_cast<const float4*>(xb + (wave * 4 + r) * DD +
                                                 i * 256 + lane * 4);

  // ---- Row norms (wave-local; butterfly leaves the sum in every lane).
  float inv[4];
#pragma unroll
  for (int r = 0; r < 4; ++r) {
    float ss = 0.0f;
#pragma unroll
    for (int i = 0; i < 4; ++i)
      ss += v[r][i].x * v[r][i].x + v[r][i].y * v[r][i].y +
            v[r][i].z * v[r][i].z + v[r][i].w * v[r][i].w;
#pragma unroll
    for (int off = 32; off; off >>= 1) ss += __shfl_xor(ss, off);
    inv[r] = 1.0f / fmaxf(sqrtf(ss), 1e-12f);
  }

  // ---- Per-wave weighted column sums (registers only).
#pragma unroll
  for (int i = 0; i < 4; ++i) {
    float4 a = make_float4(0.f, 0.f, 0.f, 0.f);
#pragma unroll
    for (int r = 0; r < 4; ++r) {
      a.x = fmaf(v[r][i].x, inv[r], a.x);
      a.y = fmaf(v[r][i].y, inv[r], a.y);
      a.z = fmaf(v[r][i].z, inv[r], a.z);
      a.w = fmaf(v[r][i].w, inv[r], a.w);
    }
    sacc[(wave * 4 + i) * 64 + lane] = a;
  }
  __syncthreads();

  // ---- Combine the 8 wave-partials per column, square, block-reduce.
  float local = 0.0f;
  if (threadIdx.x < 256) {
    const int i = threadIdx.x >> 6;
    float4 s4 = make_float4(0.f, 0.f, 0.f, 0.f);
#pragma unroll
    for (int w = 0; w < 8; ++w) {
      const float4 t4 = sacc[(w * 4 + i) * 64 + lane];
      s4.x += t4.x;
      s4.y += t4.y;
      s4.z += t4.z;
      s4.w += t4.w;
    }
    local = s4.x * s4.x + s4.y * s4.y + s4.z * s4.z + s4.w * s4.w;
  }
#pragma unroll
  for (int off = 32; off; off >>= 1) local += __shfl_xor(local, off);
  if (wave < 4 && lane == 0) wsum[wave] = local;
  __syncthreads();
  if (threadIdx.x == 0) {
    const float s2 = wsum[0] + wsum[1] + wsum[2] + wsum[3];
    partial[b] = (float)TT - s2 * (1.0f / (float)TT);
    // Publish partial, then take a ticket. Device-scope fence so the last
    // block (possibly on another XCD) sees our partial.
    __threadfence();
    const unsigned int old = atomicAdd(ticket, 1u);
    is_last = (old == (unsigned int)(BB - 1));
  }
  __syncthreads();

  // ---- Exactly one block runs this; reduce order is FIXED (deterministic).
  if (is_last) {
    __threadfence();  // acquire: make all partials visible
    float sred = partial[threadIdx.x] + partial[threadIdx.x + 512];
#pragma unroll
    for (int off = 32; off; off >>= 1) sred += __shfl_xor(sred, off);
    if (lane == 0) w2[wave] = sred;
    __syncthreads();
    if (threadIdx.x == 0) {
      float tot = 0.0f;
#pragma unroll
      for (int i = 0; i < 8; ++i) tot += w2[i];
      out[0] = tot * (1.0f / (float)BB);
    }
  }
}

extern "C" void kernel_launch(void* const* d_in, const int* in_sizes, int n_in,
                              void* d_out, int out_size, void* d_ws,
                              size_t ws_size, hipStream_t stream) {
  const float* x = (const float*)d_in[0];
  float* partial = (float*)d_ws;                      // 1024 floats = 4 KB
  unsigned int* ticket = (unsigned int*)((char*)d_ws + 4096);  // 4 bytes
  float* out = (float*)d_out;

  // Zero the ticket every call (d_ws is poisoned once, never re-poisoned).
  hipMemsetAsync(ticket, 0, sizeof(unsigned int), stream);
  clip_kernel<<<BB, 512, 0, stream>>>(x, partial, ticket, out);
}

// Round 7
// 27.750 us; speedup vs baseline: 3.3766x; 2.2651x over previous
//
#include <hip/hip_runtime.h>

// ClipCluLoss: inputs [B=1024, T=32, D=1024] fp32 -> scalar fp32.
// dist[b] = T - (1/T) * || sum_t x_n[b,t,:] ||^2 ; out = mean_b dist[b].
//
// Two kernels (ticket/coop-sync variants measured 2-3x SLOWER: cross-XCD
// fence+atomic epilogue costs ~70us; kernel2 tail is ~3us).
//
// kernel1: block = 1 sample, 512 threads (8 waves). Wave w owns rows
// w*4..w*4+3 (norm butterfly wave-local, inv in registers). Lane l owns
// cols {i*256 + l*4}: every global load is a contiguous 1 KB wave
// transaction. The 16 float4/thread are PINNED in VGPRs via an empty
// asm "+v" fence right after the loads — without it the compiler
// rematerializes the loads (VGPR_Count=40 measured) and reads the tile
// from memory twice.

#define TT 32
#define DD 1024
#define BB 1024

__global__ __launch_bounds__(512, 4) void clip_partial_kernel(
    const float* __restrict__ x, float* __restrict__ partial) {
  const int b = blockIdx.x;
  const float* __restrict__ xb = x + (size_t)b * (TT * DD);
  const int lane = threadIdx.x & 63;
  const int wave = threadIdx.x >> 6;  // 0..7

  __shared__ float4 sacc[8 * 4 * 64];  // 32 KB: [wave][chunk][lane]
  __shared__ float wsum[4];

  // ---- Load slice: 4 rows x 4 chunks of float4, all coalesced.
  float4 v[4][4];
#pragma unroll
  for (int r = 0; r < 4; ++r)
#pragma unroll
    for (int i = 0; i < 4; ++i)
      v[r][i] = *reinterpret_cast<const float4*>(xb + (wave * 4 + r) * DD +
                                                 i * 256 + lane * 4);

  // ---- Anti-remat fence: values become asm outputs, so the two consumers
  // below MUST read registers — the compiler cannot reload from global.
#pragma unroll
  for (int r = 0; r < 4; ++r)
#pragma unroll
    for (int i = 0; i < 4; ++i)
      asm volatile("" : "+v"(v[r][i].x), "+v"(v[r][i].y), "+v"(v[r][i].z),
                       "+v"(v[r][i].w));

  // ---- Row norms (wave-local; butterfly leaves the sum in every lane).
  float inv[4];
#pragma unroll
  for (int r = 0; r < 4; ++r) {
    float ss = 0.0f;
#pragma unroll
    for (int i = 0; i < 4; ++i)
      ss += v[r][i].x * v[r][i].x + v[r][i].y * v[r][i].y +
            v[r][i].z * v[r][i].z + v[r][i].w * v[r][i].w;
#pragma unroll
    for (int off = 32; off; off >>= 1) ss += __shfl_xor(ss, off);
    inv[r] = 1.0f / fmaxf(sqrtf(ss), 1e-12f);
  }

  // ---- Per-wave weighted column sums (registers only).
#pragma unroll
  for (int i = 0; i < 4; ++i) {
    float4 a = make_float4(0.f, 0.f, 0.f, 0.f);
#pragma unroll
    for (int r = 0; r < 4; ++r) {
      a.x = fmaf(v[r][i].x, inv[r], a.x);
      a.y = fmaf(v[r][i].y, inv[r], a.y);
      a.z = fmaf(v[r][i].z, inv[r], a.z);
      a.w = fmaf(v[r][i].w, inv[r], a.w);
    }
    sacc[(wave * 4 + i) * 64 + lane] = a;
  }
  __syncthreads();

  // ---- Combine the 8 wave-partials per column, square, block-reduce.
  float local = 0.0f;
  if (threadIdx.x < 256) {
    const int i = threadIdx.x >> 6;
    float4 s4 = make_float4(0.f, 0.f, 0.f, 0.f);
#pragma unroll
    for (int w = 0; w < 8; ++w) {
      const float4 t4 = sacc[(w * 4 + i) * 64 + lane];
      s4.x += t4.x;
      s4.y += t4.y;
      s4.z += t4.z;
      s4.w += t4.w;
    }
    local = s4.x * s4.x + s4.y * s4.y + s4.z * s4.z + s4.w * s4.w;
  }
#pragma unroll
  for (int off = 32; off; off >>= 1) local += __shfl_xor(local, off);
  if (wave < 4 && lane == 0) wsum[wave] = local;
  __syncthreads();
  if (threadIdx.x == 0) {
    const float s2 = wsum[0] + wsum[1] + wsum[2] + wsum[3];
    partial[b] = (float)TT - s2 * (1.0f / (float)TT);
  }
}

__global__ __launch_bounds__(256) void clip_reduce_kernel(
    const float* __restrict__ partial, float* __restrict__ out) {
  const int lane = threadIdx.x & 63;
  const int wave = threadIdx.x >> 6;
  const float4 v =
      *reinterpret_cast<const float4*>(partial + threadIdx.x * 4);
  float s = v.x + v.y + v.z + v.w;
#pragma unroll
  for (int off = 32; off; off >>= 1) s += __shfl_xor(s, off);
  __shared__ float wsum[4];
  if (lane == 0) wsum[wave] = s;
  __syncthreads();
  if (threadIdx.x == 0)
    out[0] = (wsum[0] + wsum[1] + wsum[2] + wsum[3]) * (1.0f / (float)BB);
}

extern "C" void kernel_launch(void* const* d_in, const int* in_sizes, int n_in,
                              void* d_out, int out_size, void* d_ws,
                              size_t ws_size, hipStream_t stream) {
  const float* x = (const float*)d_in[0];
  float* partial = (float*)d_ws;  // 1024 floats = 4 KB scratch
  float* out = (float*)d_out;

  clip_partial_kernel<<<BB, 512, 0, stream>>>(x, partial);
  clip_reduce_kernel<<<1, 256, 0, stream>>>(partial, out);
}